// Round 19
// baseline (86.768 us; speedup 1.0000x reference)
//
#include <hip/hip_runtime.h>

// Fused causal MHA on gfx950.  Pipeline (R18 = R17 + split-P batched-PV flash):
//   Per KV-tile visit: {QK_B, exp2_B, store->p_wB}, {QK_A, exp2_A, store->p_wA},
//   ONE fence, K-prefetch, then PV for BOTH items batched (shared vf) + ones-MFMA
//   denominators, one trailing fence.  A's compute hides B's LDS store->read
//   latency; 40 back-to-back PV MFMAs hide LDS read latency.  2 fences/visit
//   (was 4).  K contiguous khb[24][2048][64]; V^T tiled vtb[24][256][64][8];
//   shared-prefix pairs (A: qiA=32+p, B: qiB=31-p); fixed-max softmax.
//
// ws: xb/zb @0 (6291456) | qb @6291456 (6291456) | khb @12582912 (12582912)
//     vtb @25165824 (6291456) | wqkvT @31457280 (3538944) | woT @34996224
//     (1179648)   total 36175872 B

#define DEVINL __device__ __forceinline__

using bf16x8 = __attribute__((ext_vector_type(8))) __bf16;
using f32x4  = __attribute__((ext_vector_type(4))) float;

DEVINL unsigned short f32_bf16(float f) {
    unsigned u = __builtin_bit_cast(unsigned, f);
    return (unsigned short)((u + 0x7FFFu + ((u >> 16) & 1u)) >> 16);
}

DEVINL void gload16(const void* g, void* l) {
    __builtin_amdgcn_global_load_lds(
        (const __attribute__((address_space(1))) void*)g,
        (__attribute__((address_space(3))) void*)l, 16, 0, 0);
}

// ---------------- fused prep: convert + weight transposes ----------------
__global__ __launch_bounds__(256) void k_prep(const float* __restrict__ x,
                                              const float* __restrict__ Wq,
                                              const float* __restrict__ Wk,
                                              const float* __restrict__ Wv,
                                              const float* __restrict__ Wo,
                                              unsigned short* __restrict__ xb,
                                              unsigned short* __restrict__ wqkvT,
                                              unsigned short* __restrict__ woT) {
    __shared__ unsigned short tl[64][68];
    const int bid = blockIdx.x;
    const int t = threadIdx.x;
    if (bid < 3072) {
        int i = (bid * 256 + t) * 4;
        float4 v = *(const float4*)(x + i);
        ushort4 o;
        o.x = f32_bf16(v.x); o.y = f32_bf16(v.y); o.z = f32_bf16(v.z); o.w = f32_bf16(v.w);
        *(ushort4*)(xb + i) = o;
        return;
    }
    const int c = t & 63, r0 = t >> 6;
    if (bid < 3504) {
        const int sub = bid - 3072;          // 0..431
        const int tr = sub % 12, batch = sub / 12;   // batch 0..35
        const float* src = (batch < 12) ? Wq : (batch < 24) ? Wk : Wv;
        src += (size_t)(batch % 12) * 768 * 64;
        unsigned short* out = wqkvT + (size_t)batch * 64 * 768;
#pragma unroll
        for (int k = 0; k < 16; ++k) {
            int r = k * 4 + r0;
            tl[r][c] = f32_bf16(src[(size_t)(tr * 64 + r) * 64 + c]);
        }
        __syncthreads();
#pragma unroll
        for (int k = 0; k < 16; ++k) {
            int r2 = k * 4 + r0;
            out[(size_t)r2 * 768 + tr * 64 + c] = tl[c][r2];
        }
    } else {
        const int sub = bid - 3504;          // 0..143
        const int tr = sub % 12, tc = sub / 12;
#pragma unroll
        for (int k = 0; k < 16; ++k) {
            int r = k * 4 + r0;
            tl[r][c] = f32_bf16(Wo[(size_t)(tr * 64 + r) * 768 + tc * 64 + c]);
        }
        __syncthreads();
#pragma unroll
        for (int k = 0; k < 16; ++k) {
            int r2 = k * 4 + r0;
            woT[(size_t)(tc * 64 + r2) * 768 + tr * 64 + c] = tl[c][r2];
        }
    }
}

// ---------------- GEMM: C[4096][N] = A[4096][768] @ BT[N][768] + bias ----------------
// BK=64, 2-phase dbuf, source-chunk-XOR-swizzled gload_lds staging.
template <int BM, int BN, bool QKV>
__global__ __launch_bounds__(256) void k_gemm(const unsigned short* __restrict__ A,
                                              const unsigned short* __restrict__ BT,
                                              const float* __restrict__ b0,
                                              const float* __restrict__ b1,
                                              const float* __restrict__ b2,
                                              unsigned short* __restrict__ qb,
                                              unsigned short* __restrict__ khb,
                                              unsigned short* __restrict__ vtb,
                                              float* __restrict__ outf) {
    constexpr int WM = BM / 2, WN = BN / 2, MR = WM / 16, NR = WN / 16;
    __shared__ alignas(16) unsigned short As[2][BM * 64];
    __shared__ alignas(16) unsigned short Bs[2][BN * 64];
    const int t = threadIdx.x;
    const int w = t >> 6, l = t & 63, lr = l & 15, lg = l >> 4;
    const int wr = (w >> 1) * WM, wc = (w & 1) * WN;
    const int m0 = blockIdx.y * BM;
    const int n0 = blockIdx.x * BN;

    auto stage = [&](int buf, int kt) {
        const int k0 = kt * 64;
#pragma unroll
        for (int i = 0; i < BM / 32; ++i) {
            const int s = i * 256 + t;
            const int row = s >> 3, cs = (s & 7) ^ (row & 7);
            gload16((const char*)A + ((size_t)(m0 + row) * 768 + k0) * 2 + cs * 16,
                    (char*)As[buf] + s * 16);
        }
#pragma unroll
        for (int i = 0; i < BN / 32; ++i) {
            const int s = i * 256 + t;
            const int row = s >> 3, cs = (s & 7) ^ (row & 7);
            gload16((const char*)BT + ((size_t)(n0 + row) * 768 + k0) * 2 + cs * 16,
                    (char*)Bs[buf] + s * 16);
        }
    };

    stage(0, 0);
    __syncthreads();

    f32x4 acc[MR][NR] = {};

    for (int kt = 0; kt < 12; ++kt) {
        const int cur = kt & 1;
        if (kt < 11) stage(cur ^ 1, kt + 1);

        bf16x8 af[MR][2], bfr[NR][2];
#pragma unroll
        for (int ri = 0; ri < MR; ++ri)
#pragma unroll
            for (int kk = 0; kk < 2; ++kk)
                af[ri][kk] = *(const bf16x8*)&As[cur][(wr + ri * 16 + lr) * 64 +
                                                     (((kk * 4 + lg) ^ (lr & 7)) << 3)];
#pragma unroll
        for (int cj = 0; cj < NR; ++cj)
#pragma unroll
            for (int kk = 0; kk < 2; ++kk)
                bfr[cj][kk] = *(const bf16x8*)&Bs[cur][(wc + cj * 16 + lr) * 64 +
                                                       (((kk * 4 + lg) ^ (lr & 7)) << 3)];
        __builtin_amdgcn_s_setprio(1);
#pragma unroll
        for (int ri = 0; ri < MR; ++ri)
#pragma unroll
            for (int cj = 0; cj < NR; ++cj) {
                acc[ri][cj] = __builtin_amdgcn_mfma_f32_16x16x32_bf16(
                    af[ri][0], bfr[cj][0], acc[ri][cj], 0, 0, 0);
                acc[ri][cj] = __builtin_amdgcn_mfma_f32_16x16x32_bf16(
                    af[ri][1], bfr[cj][1], acc[ri][cj], 0, 0, 0);
            }
        __builtin_amdgcn_s_setprio(0);
        __syncthreads();
    }

#pragma unroll
    for (int cj = 0; cj < NR; ++cj) {
        const int col = n0 + wc + cj * 16 + lr;
        if (QKV && col >= 1536) {
            // ---- V cols: vtb[bh][s>>3][d][s&7], ushort4 over e (s..s+3) ----
            const int vc = col - 1536;
            const float bv = b2[vc];
            const int hh = vc >> 6, dd = vc & 63;
#pragma unroll
            for (int ri = 0; ri < MR; ++ri) {
                const int row = m0 + wr + ri * 16 + lg * 4;   // s%8 in {0,4}
                const int bb = row >> 11, s = row & 2047;
                ushort4 pkv;
                pkv.x = f32_bf16(acc[ri][cj][0] + bv);
                pkv.y = f32_bf16(acc[ri][cj][1] + bv);
                pkv.z = f32_bf16(acc[ri][cj][2] + bv);
                pkv.w = f32_bf16(acc[ri][cj][3] + bv);
                *(ushort4*)(vtb + (size_t)(bb * 12 + hh) * 131072 +
                            (s >> 3) * 512 + dd * 8 + (s & 7)) = pkv;
            }
        } else if (QKV && col >= 768) {
            // ---- K cols: khb[bh][s][64] contiguous per head ----
            const int kc = col - 768;
            const float bv = b1[kc];
            const int hh = kc >> 6, dd = kc & 63;
#pragma unroll
            for (int ri = 0; ri < MR; ++ri)
#pragma unroll
                for (int e = 0; e < 4; ++e) {
                    const int row = m0 + wr + ri * 16 + lg * 4 + e;
                    const int bb = row >> 11, s = row & 2047;
                    khb[(size_t)(bb * 12 + hh) * 131072 + s * 64 + dd] =
                        f32_bf16(acc[ri][cj][e] + bv);
                }
        } else {
            const float bv = b0[col];
            const float scl = QKV ? 0.18033688011112042f : 1.0f;  // 0.125*log2e
#pragma unroll
            for (int ri = 0; ri < MR; ++ri)
#pragma unroll
                for (int e = 0; e < 4; ++e) {
                    const int row = m0 + wr + ri * 16 + lg * 4 + e;
                    const float v = (acc[ri][cj][e] + bv) * scl;
                    if (QKV) qb[(size_t)row * 768 + col] = f32_bf16(v);
                    else     outf[(size_t)row * 768 + col] = v;
                }
        }
    }
}

// ---------------- flash: shared-prefix pairs, split-P, batched PV ----------------
// grid (hb=24, p=32), 256 thr.  Item A: qiA=32+p; item B: qiB=31-p (same b,h).
// Per-wave P buffers: p_wB = smem + w*4096 ; p_wA = smem + 16384 + w*4096
// (both alias the 4x8704 merge region, dead during the loop).
__global__ __launch_bounds__(256) void k_flash(const unsigned short* __restrict__ qb,
                                               const unsigned short* __restrict__ khb,
                                               const unsigned short* __restrict__ vtb,
                                               unsigned short* __restrict__ zb) {
    __shared__ alignas(16) char smem[4 * 8704 + 1024];
    const int hb = blockIdx.x;              // 0..23
    const int h = hb % 12, b = hb / 12;
    const int p = blockIdx.y;               // 0..31
    const int qiA = 32 + p, qiB = 31 - p;
    const int q0A = qiA * 32, q0B = qiB * 32;
    const int nkvA = (qiA >> 1) + 1, nkvB = (qiB >> 1) + 1;
    const int t = threadIdx.x, w = t >> 6, l = t & 63, lr = l & 15, lg = l >> 4;

    char* p_wB = smem + w * 4096;
    char* p_wA = smem + 16384 + w * 4096;
    float* lldsA = (float*)(smem + 4 * 8704);          // [4][32]
    float* lldsB = (float*)(smem + 4 * 8704 + 512);    // [4][32]

    // all-ones A-fragment (bf16 1.0 = 0x3F80)
    bf16x8 vones;
#pragma unroll
    for (int j = 0; j < 8; ++j)
        vones[j] = __builtin_bit_cast(__bf16, (unsigned short)0x3F80);

    const size_t qrowbase = (size_t)(b * 2048) * 768;
    bf16x8 qfA[2][2], qfB[2][2];
#pragma unroll
    for (int ri = 0; ri < 2; ++ri)
#pragma unroll
        for (int kk = 0; kk < 2; ++kk) {
            qfA[ri][kk] = *(const bf16x8*)(qb + qrowbase +
                                           (size_t)(q0A + ri * 16 + lr) * 768 +
                                           h * 64 + kk * 32 + lg * 8);
            qfB[ri][kk] = *(const bf16x8*)(qb + qrowbase +
                                           (size_t)(q0B + ri * 16 + lr) * 768 +
                                           h * 64 + kk * 32 + lg * 8);
        }

    f32x4 oA[2][4] = {}, oB[2][4] = {};
    f32x4 oDA[2] = {}, oDB[2] = {};     // denominators via ones-MFMA

    const unsigned short* kh = khb + (size_t)(b * 12 + h) * 131072;  // [2048][64]
    const unsigned short* vt = vtb + (size_t)(b * 12 + h) * 131072;  // [256][64][8]

    {
        bf16x8 kf[4][2];
        auto loadK = [&](int kv0) {
#pragma unroll
            for (int cj = 0; cj < 4; ++cj)
#pragma unroll
                for (int kk = 0; kk < 2; ++kk)
                    kf[cj][kk] = *(const bf16x8*)(kh + (size_t)(kv0 + cj * 16 + lr) * 64 +
                                                  kk * 32 + lg * 8);
        };

        int kt = w;                // nkvA >= 17 > 4, so every wave has work
        loadK(kt * 64);
        do {
            const int kv0 = kt * 64;
            const bool doB = (kt < nkvB);

            // V fragments issued FIRST -> latency covered by both items' compute
            bf16x8 vf[2][4];
#pragma unroll
            for (int kk = 0; kk < 2; ++kk)
#pragma unroll
                for (int dj = 0; dj < 4; ++dj)
                    vf[kk][dj] = *(const bf16x8*)(vt + (size_t)((kv0 >> 3) + kk * 4 + lg) * 512 +
                                                  (dj * 16 + lr) * 8);

            const f32x4 zz = {0.f, 0.f, 0.f, 0.f};

            // ---- item B: QK, softmax, store -> p_wB ----
            if (doB) {
                f32x4 st[2][4];
                __builtin_amdgcn_s_setprio(1);
#pragma unroll
                for (int ri = 0; ri < 2; ++ri)
#pragma unroll
                    for (int cj = 0; cj < 4; ++cj) {
                        f32x4 a0 = __builtin_amdgcn_mfma_f32_16x16x32_bf16(kf[cj][0], qfB[ri][0], zz, 0, 0, 0);
                        st[ri][cj] = __builtin_amdgcn_mfma_f32_16x16x32_bf16(kf[cj][1], qfB[ri][1], a0, 0, 0, 0);
                    }
                __builtin_amdgcn_s_setprio(0);

                if (kt == nkvB - 1) {
#pragma unroll
                    for (int ri = 0; ri < 2; ++ri)
#pragma unroll
                        for (int cj = 0; cj < 4; ++cj)
#pragma unroll
                            for (int e = 0; e < 4; ++e) {
                                const int kvv = kv0 + cj * 16 + lg * 4 + e;
                                const int qq  = q0B + ri * 16 + lr;
                                if (kvv > qq) st[ri][cj][e] = -1e30f;
                            }
                }

#pragma unroll
                for (int ri = 0; ri < 2; ++ri) {
#pragma unroll
                    for (int cj = 0; cj < 4; ++cj)
#pragma unroll
                        for (int e = 0; e < 4; ++e)
                            st[ri][cj][e] = __builtin_amdgcn_exp2f(st[ri][cj][e]);
                    const int row = ri * 16 + lr;
#pragma unroll
                    for (int cj = 0; cj < 4; ++cj) {
                        unsigned lo, hi;
                        asm("v_cvt_pk_bf16_f32 %0, %1, %2"
                            : "=v"(lo) : "v"(st[ri][cj][0]), "v"(st[ri][cj][1]));
                        asm("v_cvt_pk_bf16_f32 %0, %1, %2"
                            : "=v"(hi) : "v"(st[ri][cj][2]), "v"(st[ri][cj][3]));
                        const int gr = (cj * 2 + (lg >> 1)) ^ (lr & 7);
                        uint2 pk2; pk2.x = lo; pk2.y = hi;
                        *(uint2*)(p_wB + row * 128 + gr * 16 + (lg & 1) * 8) = pk2;
                    }
                }
            }

            // ---- item A: QK, softmax, store -> p_wA ----
            {
                f32x4 st[2][4];
                __builtin_amdgcn_s_setprio(1);
#pragma unroll
                for (int ri = 0; ri < 2; ++ri)
#pragma unroll
                    for (int cj = 0; cj < 4; ++cj) {
                        f32x4 a0 = __builtin_amdgcn_mfma_f32_16x16x32_bf16(kf[cj][0], qfA[ri][0], zz, 0, 0, 0);
                        st[ri][cj] = __builtin_amdgcn_mfma_f32_16x16x32_bf16(kf[cj][1], qfA[ri][1], a0, 0, 0, 0);
                    }
                __builtin_amdgcn_s_setprio(0);

                if (kt == nkvA - 1) {
#pragma unroll
                    for (int ri = 0; ri < 2; ++ri)
#pragma unroll
                        for (int cj = 0; cj < 4; ++cj)
#pragma unroll
                            for (int e = 0; e < 4; ++e) {
                                const int kvv = kv0 + cj * 16 + lg * 4 + e;
                                const int qq  = q0A + ri * 16 + lr;
                                if (kvv > qq) st[ri][cj][e] = -1e30f;
                            }
                }

#pragma unroll
                for (int ri = 0; ri < 2; ++ri) {
#pragma unroll
                    for (int cj = 0; cj < 4; ++cj)
#pragma unroll
                        for (int e = 0; e < 4; ++e)
                            st[ri][cj][e] = __builtin_amdgcn_exp2f(st[ri][cj][e]);
                    const int row = ri * 16 + lr;
#pragma unroll
                    for (int cj = 0; cj < 4; ++cj) {
                        unsigned lo, hi;
                        asm("v_cvt_pk_bf16_f32 %0, %1, %2"
                            : "=v"(lo) : "v"(st[ri][cj][0]), "v"(st[ri][cj][1]));
                        asm("v_cvt_pk_bf16_f32 %0, %1, %2"
                            : "=v"(hi) : "v"(st[ri][cj][2]), "v"(st[ri][cj][3]));
                        const int gr = (cj * 2 + (lg >> 1)) ^ (lr & 7);
                        uint2 pk2; pk2.x = lo; pk2.y = hi;
                        *(uint2*)(p_wA + row * 128 + gr * 16 + (lg & 1) * 8) = pk2;
                    }
                }
            }

            // single fence: all P-stores complete before any pa read below
            asm volatile("" ::: "memory");

            // prefetch next K tile (kf dead) under the PV cluster
            const bool more = (kt + 4 < nkvA);
            if (more) loadK(kv0 + 256);

            // ---- batched PV for both items (shared vf) ----
            __builtin_amdgcn_s_setprio(1);
#pragma unroll
            for (int kk = 0; kk < 2; ++kk)
#pragma unroll
                for (int ri = 0; ri < 2; ++ri) {
                    const int row = ri * 16 + lr;
                    const int g = (kk * 4 + lg) ^ (lr & 7);
                    bf16x8 paA = *(const bf16x8*)(p_wA + row * 128 + g * 16);
#pragma unroll
                    for (int dj = 0; dj < 4; ++dj)
                        oA[ri][dj] = __builtin_amdgcn_mfma_f32_16x16x32_bf16(
                            vf[kk][dj], paA, oA[ri][dj], 0, 0, 0);
                    oDA[ri] = __builtin_amdgcn_mfma_f32_16x16x32_bf16(
                        vones, paA, oDA[ri], 0, 0, 0);
                    if (doB) {
                        bf16x8 paB = *(const bf16x8*)(p_wB + row * 128 + g * 16);
#pragma unroll
                        for (int dj = 0; dj < 4; ++dj)
                            oB[ri][dj] = __builtin_amdgcn_mfma_f32_16x16x32_bf16(
                                vf[kk][dj], paB, oB[ri][dj], 0, 0, 0);
                        oDB[ri] = __builtin_amdgcn_mfma_f32_16x16x32_bf16(
                            vones, paB, oDB[ri], 0, 0, 0);
                    }
                }
            __builtin_amdgcn_s_setprio(0);

            // fence: next iteration's P-stores must not be hoisted above pa reads
            asm volatile("" ::: "memory");

            kt += 4;
        } while (kt < nkvA);
    }

    // ---- denominators: every lane already holds its q-column's partial sum ----
    if (lg == 0) {
#pragma unroll
        for (int ri = 0; ri < 2; ++ri) {
            lldsA[w * 32 + ri * 16 + lr] = oDA[ri][0];
            lldsB[w * 32 + ri * 16 + lr] = oDB[ri][0];
        }
    }
    __syncthreads();   // loops done; P regions dead; llds complete

    // ---- merge item A, then item B (reusing scratch) ----
#pragma unroll
    for (int item = 0; item < 2; ++item) {
        const float* lld = item ? lldsB : lldsA;
        const int q0 = item ? q0B : q0A;
        float* o_w = (float*)(smem + w * 8704);  // [32][68] f32
#pragma unroll
        for (int ri = 0; ri < 2; ++ri) {
            const int row = ri * 16 + lr;
#pragma unroll
            for (int dj = 0; dj < 4; ++dj)
                *(f32x4*)&o_w[row * 68 + dj * 16 + lg * 4] = item ? oB[ri][dj] : oA[ri][dj];
        }
        __syncthreads();
        {
            const int row = w * 8 + (l >> 3);
            const int c0 = (l & 7) * 8;
            const float lt = lld[row] + lld[32 + row] + lld[64 + row] + lld[96 + row];
            const float inv = 1.0f / lt;
            ushort4 pk[2];
#pragma unroll
            for (int half = 0; half < 2; ++half) {
                unsigned short u[4];
#pragma unroll
                for (int k = 0; k < 4; ++k) {
                    float acc = 0.f;
#pragma unroll
                    for (int s = 0; s < 4; ++s)
                        acc += ((const float*)(smem + s * 8704))[row * 68 + c0 + half * 4 + k];
                    u[k] = f32_bf16(acc * inv);
                }
                pk[half] = make_ushort4(u[0], u[1], u[2], u[3]);
            }
            unsigned short* dst = zb + (size_t)(b * 2048 + q0 + row) * 768 + h * 64 + c0;
            *(ushort4*)dst = pk[0];
            *(ushort4*)(dst + 4) = pk[1];
        }
        __syncthreads();
    }
}

extern "C" void kernel_launch(void* const* d_in, const int* in_sizes, int n_in,
                              void* d_out, int out_size, void* d_ws, size_t ws_size,
                              hipStream_t stream) {
    (void)in_sizes; (void)n_in; (void)out_size; (void)ws_size;
    const float* x   = (const float*)d_in[0];
    const float* W_Q = (const float*)d_in[1];
    const float* W_K = (const float*)d_in[2];
    const float* W_V = (const float*)d_in[3];
    const float* b_Q = (const float*)d_in[4];
    const float* b_K = (const float*)d_in[5];
    const float* b_V = (const float*)d_in[6];
    const float* W_O = (const float*)d_in[7];
    const float* b_O = (const float*)d_in[8];
    float* out = (float*)d_out;

    char* ws = (char*)d_ws;
    unsigned short* xb    = (unsigned short*)(ws);
    unsigned short* qb    = (unsigned short*)(ws + 6291456);
    unsigned short* khb   = (unsigned short*)(ws + 12582912);
    unsigned short* vtb   = (unsigned short*)(ws + 25165824);
    unsigned short* wqkvT = (unsigned short*)(ws + 31457280);
    unsigned short* woT   = (unsigned short*)(ws + 34996224);
    unsigned short* zb    = xb;  // xb dead after the QKV GEMM

    k_prep<<<3648, 256, 0, stream>>>(x, W_Q, W_K, W_V, W_O, xb, wqkvT, woT);

    k_gemm<128, 64, true><<<dim3(36, 32), 256, 0, stream>>>(xb, wqkvT, b_Q, b_K, b_V,
                                                            qb, khb, vtb, nullptr);

    k_flash<<<dim3(24, 32), 256, 0, stream>>>(qb, khb, vtb, zb);

    k_gemm<64, 64, false><<<dim3(12, 64), 256, 0, stream>>>(zb, woT, b_O, b_O, b_O,
                                                            nullptr, nullptr, nullptr, out);
}

// Round 20
// 85.796 us; speedup vs baseline: 1.0113x; 1.0113x over previous
//
#include <hip/hip_runtime.h>

// Fused causal MHA on gfx950.  Pipeline (R19 = revert to R16, best measured):
//   K/V addressing fix: K per-head contiguous khb[24][2048][64]; V^T kv-chunk
//   tiled vtb[24][256][64][8] (no power-of-2 channel camping).  Flash:
//   shared-prefix paired items (A: qiA=32+p, B: qiB=31-p), 768 uniform blocks,
//   fixed-max softmax P=exp2(st), swapped-operand MFMA, VALU row-sums.
//   GEMMs: BK=64 2-phase dbuf, source-chunk-XOR-swizzled gload_lds.
//
// ws: xb/zb @0 (6291456) | qb @6291456 (6291456) | khb @12582912 (12582912)
//     vtb @25165824 (6291456) | wqkvT @31457280 (3538944) | woT @34996224
//     (1179648)   total 36175872 B

#define DEVINL __device__ __forceinline__

using bf16x8 = __attribute__((ext_vector_type(8))) __bf16;
using f32x4  = __attribute__((ext_vector_type(4))) float;

DEVINL unsigned short f32_bf16(float f) {
    unsigned u = __builtin_bit_cast(unsigned, f);
    return (unsigned short)((u + 0x7FFFu + ((u >> 16) & 1u)) >> 16);
}

DEVINL void gload16(const void* g, void* l) {
    __builtin_amdgcn_global_load_lds(
        (const __attribute__((address_space(1))) void*)g,
        (__attribute__((address_space(3))) void*)l, 16, 0, 0);
}

// ---------------- fused prep: convert + weight transposes ----------------
__global__ __launch_bounds__(256) void k_prep(const float* __restrict__ x,
                                              const float* __restrict__ Wq,
                                              const float* __restrict__ Wk,
                                              const float* __restrict__ Wv,
                                              const float* __restrict__ Wo,
                                              unsigned short* __restrict__ xb,
                                              unsigned short* __restrict__ wqkvT,
                                              unsigned short* __restrict__ woT) {
    __shared__ unsigned short tl[64][68];
    const int bid = blockIdx.x;
    const int t = threadIdx.x;
    if (bid < 3072) {
        int i = (bid * 256 + t) * 4;
        float4 v = *(const float4*)(x + i);
        ushort4 o;
        o.x = f32_bf16(v.x); o.y = f32_bf16(v.y); o.z = f32_bf16(v.z); o.w = f32_bf16(v.w);
        *(ushort4*)(xb + i) = o;
        return;
    }
    const int c = t & 63, r0 = t >> 6;
    if (bid < 3504) {
        const int sub = bid - 3072;          // 0..431
        const int tr = sub % 12, batch = sub / 12;   // batch 0..35
        const float* src = (batch < 12) ? Wq : (batch < 24) ? Wk : Wv;
        src += (size_t)(batch % 12) * 768 * 64;
        unsigned short* out = wqkvT + (size_t)batch * 64 * 768;
#pragma unroll
        for (int k = 0; k < 16; ++k) {
            int r = k * 4 + r0;
            tl[r][c] = f32_bf16(src[(size_t)(tr * 64 + r) * 64 + c]);
        }
        __syncthreads();
#pragma unroll
        for (int k = 0; k < 16; ++k) {
            int r2 = k * 4 + r0;
            out[(size_t)r2 * 768 + tr * 64 + c] = tl[c][r2];
        }
    } else {
        const int sub = bid - 3504;          // 0..143
        const int tr = sub % 12, tc = sub / 12;
#pragma unroll
        for (int k = 0; k < 16; ++k) {
            int r = k * 4 + r0;
            tl[r][c] = f32_bf16(Wo[(size_t)(tr * 64 + r) * 768 + tc * 64 + c]);
        }
        __syncthreads();
#pragma unroll
        for (int k = 0; k < 16; ++k) {
            int r2 = k * 4 + r0;
            woT[(size_t)(tc * 64 + r2) * 768 + tr * 64 + c] = tl[c][r2];
        }
    }
}

// ---------------- GEMM: C[4096][N] = A[4096][768] @ BT[N][768] + bias ----------------
// BK=64, 2-phase dbuf, source-chunk-XOR-swizzled gload_lds staging.
// QKV=true epilogue routes: Q cols -> qb [4096][768] (scaled); K cols ->
// khb[bh][s][64] contiguous; V cols -> vtb[bh][s>>3][d][s&7] tiled.
template <int BM, int BN, bool QKV>
__global__ __launch_bounds__(256) void k_gemm(const unsigned short* __restrict__ A,
                                              const unsigned short* __restrict__ BT,
                                              const float* __restrict__ b0,
                                              const float* __restrict__ b1,
                                              const float* __restrict__ b2,
                                              unsigned short* __restrict__ qb,
                                              unsigned short* __restrict__ khb,
                                              unsigned short* __restrict__ vtb,
                                              float* __restrict__ outf) {
    constexpr int WM = BM / 2, WN = BN / 2, MR = WM / 16, NR = WN / 16;
    __shared__ alignas(16) unsigned short As[2][BM * 64];
    __shared__ alignas(16) unsigned short Bs[2][BN * 64];
    const int t = threadIdx.x;
    const int w = t >> 6, l = t & 63, lr = l & 15, lg = l >> 4;
    const int wr = (w >> 1) * WM, wc = (w & 1) * WN;
    const int m0 = blockIdx.y * BM;
    const int n0 = blockIdx.x * BN;

    auto stage = [&](int buf, int kt) {
        const int k0 = kt * 64;
#pragma unroll
        for (int i = 0; i < BM / 32; ++i) {
            const int s = i * 256 + t;
            const int row = s >> 3, cs = (s & 7) ^ (row & 7);
            gload16((const char*)A + ((size_t)(m0 + row) * 768 + k0) * 2 + cs * 16,
                    (char*)As[buf] + s * 16);
        }
#pragma unroll
        for (int i = 0; i < BN / 32; ++i) {
            const int s = i * 256 + t;
            const int row = s >> 3, cs = (s & 7) ^ (row & 7);
            gload16((const char*)BT + ((size_t)(n0 + row) * 768 + k0) * 2 + cs * 16,
                    (char*)Bs[buf] + s * 16);
        }
    };

    stage(0, 0);
    __syncthreads();

    f32x4 acc[MR][NR] = {};

    for (int kt = 0; kt < 12; ++kt) {
        const int cur = kt & 1;
        if (kt < 11) stage(cur ^ 1, kt + 1);

        bf16x8 af[MR][2], bfr[NR][2];
#pragma unroll
        for (int ri = 0; ri < MR; ++ri)
#pragma unroll
            for (int kk = 0; kk < 2; ++kk)
                af[ri][kk] = *(const bf16x8*)&As[cur][(wr + ri * 16 + lr) * 64 +
                                                     (((kk * 4 + lg) ^ (lr & 7)) << 3)];
#pragma unroll
        for (int cj = 0; cj < NR; ++cj)
#pragma unroll
            for (int kk = 0; kk < 2; ++kk)
                bfr[cj][kk] = *(const bf16x8*)&Bs[cur][(wc + cj * 16 + lr) * 64 +
                                                       (((kk * 4 + lg) ^ (lr & 7)) << 3)];
        __builtin_amdgcn_s_setprio(1);
#pragma unroll
        for (int ri = 0; ri < MR; ++ri)
#pragma unroll
            for (int cj = 0; cj < NR; ++cj) {
                acc[ri][cj] = __builtin_amdgcn_mfma_f32_16x16x32_bf16(
                    af[ri][0], bfr[cj][0], acc[ri][cj], 0, 0, 0);
                acc[ri][cj] = __builtin_amdgcn_mfma_f32_16x16x32_bf16(
                    af[ri][1], bfr[cj][1], acc[ri][cj], 0, 0, 0);
            }
        __builtin_amdgcn_s_setprio(0);
        __syncthreads();
    }

#pragma unroll
    for (int cj = 0; cj < NR; ++cj) {
        const int col = n0 + wc + cj * 16 + lr;
        if (QKV && col >= 1536) {
            // ---- V cols: vtb[bh][s>>3][d][s&7], ushort4 over e (s..s+3) ----
            const int vc = col - 1536;
            const float bv = b2[vc];
            const int hh = vc >> 6, dd = vc & 63;
#pragma unroll
            for (int ri = 0; ri < MR; ++ri) {
                const int row = m0 + wr + ri * 16 + lg * 4;   // s%8 in {0,4}
                const int bb = row >> 11, s = row & 2047;
                ushort4 pkv;
                pkv.x = f32_bf16(acc[ri][cj][0] + bv);
                pkv.y = f32_bf16(acc[ri][cj][1] + bv);
                pkv.z = f32_bf16(acc[ri][cj][2] + bv);
                pkv.w = f32_bf16(acc[ri][cj][3] + bv);
                *(ushort4*)(vtb + (size_t)(bb * 12 + hh) * 131072 +
                            (s >> 3) * 512 + dd * 8 + (s & 7)) = pkv;
            }
        } else if (QKV && col >= 768) {
            // ---- K cols: khb[bh][s][64] contiguous per head ----
            const int kc = col - 768;
            const float bv = b1[kc];
            const int hh = kc >> 6, dd = kc & 63;
#pragma unroll
            for (int ri = 0; ri < MR; ++ri)
#pragma unroll
                for (int e = 0; e < 4; ++e) {
                    const int row = m0 + wr + ri * 16 + lg * 4 + e;
                    const int bb = row >> 11, s = row & 2047;
                    khb[(size_t)(bb * 12 + hh) * 131072 + s * 64 + dd] =
                        f32_bf16(acc[ri][cj][e] + bv);
                }
        } else {
            const float bv = b0[col];
            const float scl = QKV ? 0.18033688011112042f : 1.0f;  // 0.125*log2e
#pragma unroll
            for (int ri = 0; ri < MR; ++ri)
#pragma unroll
                for (int e = 0; e < 4; ++e) {
                    const int row = m0 + wr + ri * 16 + lg * 4 + e;
                    const float v = (acc[ri][cj][e] + bv) * scl;
                    if (QKV) qb[(size_t)row * 768 + col] = f32_bf16(v);
                    else     outf[(size_t)row * 768 + col] = v;
                }
        }
    }
}

// ---------------- flash attention: shared-prefix paired items (R16, verified) ---------
// grid (hb=24, p=32), 256 thr.  Item A: qiA=32+p; item B: qiB=31-p (same b,h).
// K from khb (contiguous 128B rows); V from tiled vtb (coalesced 256B segments).
#define WREG 8704
__global__ __launch_bounds__(256) void k_flash(const unsigned short* __restrict__ qb,
                                               const unsigned short* __restrict__ khb,
                                               const unsigned short* __restrict__ vtb,
                                               unsigned short* __restrict__ zb) {
    __shared__ alignas(16) char smem[4 * WREG + 1024];
    const int hb = blockIdx.x;              // 0..23
    const int h = hb % 12, b = hb / 12;
    const int p = blockIdx.y;               // 0..31
    const int qiA = 32 + p, qiB = 31 - p;
    const int q0A = qiA * 32, q0B = qiB * 32;
    const int nkvA = (qiA >> 1) + 1, nkvB = (qiB >> 1) + 1;
    const int t = threadIdx.x, w = t >> 6, l = t & 63, lr = l & 15, lg = l >> 4;

    char* p_w = smem + w * WREG;                       // P[q][kv] bf16, swizzled
    float* lldsA = (float*)(smem + 4 * WREG);          // [4][32]
    float* lldsB = (float*)(smem + 4 * WREG + 512);    // [4][32]

    const size_t qrowbase = (size_t)(b * 2048) * 768;
    bf16x8 qfA[2][2], qfB[2][2];
#pragma unroll
    for (int ri = 0; ri < 2; ++ri)
#pragma unroll
        for (int kk = 0; kk < 2; ++kk) {
            qfA[ri][kk] = *(const bf16x8*)(qb + qrowbase +
                                           (size_t)(q0A + ri * 16 + lr) * 768 +
                                           h * 64 + kk * 32 + lg * 8);
            qfB[ri][kk] = *(const bf16x8*)(qb + qrowbase +
                                           (size_t)(q0B + ri * 16 + lr) * 768 +
                                           h * 64 + kk * 32 + lg * 8);
        }

    f32x4 oA[2][4] = {}, oB[2][4] = {};
    float lsA[2] = {0.f, 0.f}, lsB[2] = {0.f, 0.f};

    const unsigned short* kh = khb + (size_t)(b * 12 + h) * 131072;  // [2048][64]
    const unsigned short* vt = vtb + (size_t)(b * 12 + h) * 131072;  // [256][64][8]

    {
        bf16x8 kf[4][2];
        auto loadK = [&](int kv0) {
#pragma unroll
            for (int cj = 0; cj < 4; ++cj)
#pragma unroll
                for (int kk = 0; kk < 2; ++kk)
                    kf[cj][kk] = *(const bf16x8*)(kh + (size_t)(kv0 + cj * 16 + lr) * 64 +
                                                  kk * 32 + lg * 8);
        };

        int kt = w;                // nkvA >= 17 > 4, so every wave has work
        loadK(kt * 64);
        do {
            const int kv0 = kt * 64;

            // V fragments issued FIRST -> latency covered by B+A compute.
            // Tiled layout: chunk = (kv0>>3)+kk*4+lg, addr = chunk*512 + d*8.
            bf16x8 vf[2][4];
#pragma unroll
            for (int kk = 0; kk < 2; ++kk)
#pragma unroll
                for (int dj = 0; dj < 4; ++dj)
                    vf[kk][dj] = *(const bf16x8*)(vt + (size_t)((kv0 >> 3) + kk * 4 + lg) * 512 +
                                                  (dj * 16 + lr) * 8);

            const f32x4 zz = {0.f, 0.f, 0.f, 0.f};

            // ================= item B (prefix rider) =================
            if (kt < nkvB) {
                f32x4 st[2][4];
                __builtin_amdgcn_s_setprio(1);
#pragma unroll
                for (int ri = 0; ri < 2; ++ri)
#pragma unroll
                    for (int cj = 0; cj < 4; ++cj) {
                        f32x4 a0 = __builtin_amdgcn_mfma_f32_16x16x32_bf16(kf[cj][0], qfB[ri][0], zz, 0, 0, 0);
                        st[ri][cj] = __builtin_amdgcn_mfma_f32_16x16x32_bf16(kf[cj][1], qfB[ri][1], a0, 0, 0, 0);
                    }
                __builtin_amdgcn_s_setprio(0);

                if (kt == nkvB - 1) {
#pragma unroll
                    for (int ri = 0; ri < 2; ++ri)
#pragma unroll
                        for (int cj = 0; cj < 4; ++cj)
#pragma unroll
                            for (int e = 0; e < 4; ++e) {
                                const int kvv = kv0 + cj * 16 + lg * 4 + e;
                                const int qq  = q0B + ri * 16 + lr;
                                if (kvv > qq) st[ri][cj][e] = -1e30f;
                            }
                }

#pragma unroll
                for (int ri = 0; ri < 2; ++ri) {
                    float ps = 0.f;
#pragma unroll
                    for (int cj = 0; cj < 4; ++cj)
#pragma unroll
                        for (int e = 0; e < 4; ++e) {
                            const float pv = __builtin_amdgcn_exp2f(st[ri][cj][e]);
                            st[ri][cj][e] = pv;
                            ps += pv;
                        }
                    lsB[ri] += ps;

                    const int row = ri * 16 + lr;
#pragma unroll
                    for (int cj = 0; cj < 4; ++cj) {
                        unsigned lo, hi;
                        asm("v_cvt_pk_bf16_f32 %0, %1, %2"
                            : "=v"(lo) : "v"(st[ri][cj][0]), "v"(st[ri][cj][1]));
                        asm("v_cvt_pk_bf16_f32 %0, %1, %2"
                            : "=v"(hi) : "v"(st[ri][cj][2]), "v"(st[ri][cj][3]));
                        const int gr = (cj * 2 + (lg >> 1)) ^ (lr & 7);
                        uint2 pk2; pk2.x = lo; pk2.y = hi;
                        *(uint2*)(p_w + row * 128 + gr * 16 + (lg & 1) * 8) = pk2;
                    }
                }

                asm volatile("" ::: "memory");

                __builtin_amdgcn_s_setprio(1);
#pragma unroll
                for (int kk = 0; kk < 2; ++kk)
#pragma unroll
                    for (int ri = 0; ri < 2; ++ri) {
                        const int row = ri * 16 + lr;
                        const int g = (kk * 4 + lg) ^ (lr & 7);
                        bf16x8 pa = *(const bf16x8*)(p_w + row * 128 + g * 16);
#pragma unroll
                        for (int dj = 0; dj < 4; ++dj)
                            oB[ri][dj] = __builtin_amdgcn_mfma_f32_16x16x32_bf16(
                                vf[kk][dj], pa, oB[ri][dj], 0, 0, 0);
                    }
                __builtin_amdgcn_s_setprio(0);

                asm volatile("" ::: "memory");
            }

            // ================= item A =================
            {
                f32x4 st[2][4];
                __builtin_amdgcn_s_setprio(1);
#pragma unroll
                for (int ri = 0; ri < 2; ++ri)
#pragma unroll
                    for (int cj = 0; cj < 4; ++cj) {
                        f32x4 a0 = __builtin_amdgcn_mfma_f32_16x16x32_bf16(kf[cj][0], qfA[ri][0], zz, 0, 0, 0);
                        st[ri][cj] = __builtin_amdgcn_mfma_f32_16x16x32_bf16(kf[cj][1], qfA[ri][1], a0, 0, 0, 0);
                    }
                __builtin_amdgcn_s_setprio(0);

                if (kt == nkvA - 1) {
#pragma unroll
                    for (int ri = 0; ri < 2; ++ri)
#pragma unroll
                        for (int cj = 0; cj < 4; ++cj)
#pragma unroll
                            for (int e = 0; e < 4; ++e) {
                                const int kvv = kv0 + cj * 16 + lg * 4 + e;
                                const int qq  = q0A + ri * 16 + lr;
                                if (kvv > qq) st[ri][cj][e] = -1e30f;
                            }
                }

#pragma unroll
                for (int ri = 0; ri < 2; ++ri) {
                    float ps = 0.f;
#pragma unroll
                    for (int cj = 0; cj < 4; ++cj)
#pragma unroll
                        for (int e = 0; e < 4; ++e) {
                            const float pv = __builtin_amdgcn_exp2f(st[ri][cj][e]);
                            st[ri][cj][e] = pv;
                            ps += pv;
                        }
                    lsA[ri] += ps;

                    const int row = ri * 16 + lr;
#pragma unroll
                    for (int cj = 0; cj < 4; ++cj) {
                        unsigned lo, hi;
                        asm("v_cvt_pk_bf16_f32 %0, %1, %2"
                            : "=v"(lo) : "v"(st[ri][cj][0]), "v"(st[ri][cj][1]));
                        asm("v_cvt_pk_bf16_f32 %0, %1, %2"
                            : "=v"(hi) : "v"(st[ri][cj][2]), "v"(st[ri][cj][3]));
                        const int gr = (cj * 2 + (lg >> 1)) ^ (lr & 7);
                        uint2 pk2; pk2.x = lo; pk2.y = hi;
                        *(uint2*)(p_w + row * 128 + gr * 16 + (lg & 1) * 8) = pk2;
                    }
                }

                asm volatile("" ::: "memory");

                // prefetch next K tile (kf dead after A-QK) under A's PV
                const bool more = (kt + 4 < nkvA);
                if (more) loadK(kv0 + 256);

                __builtin_amdgcn_s_setprio(1);
#pragma unroll
                for (int kk = 0; kk < 2; ++kk)
#pragma unroll
                    for (int ri = 0; ri < 2; ++ri) {
                        const int row = ri * 16 + lr;
                        const int g = (kk * 4 + lg) ^ (lr & 7);
                        bf16x8 pa = *(const bf16x8*)(p_w + row * 128 + g * 16);
#pragma unroll
                        for (int dj = 0; dj < 4; ++dj)
                            oA[ri][dj] = __builtin_amdgcn_mfma_f32_16x16x32_bf16(
                                vf[kk][dj], pa, oA[ri][dj], 0, 0, 0);
                    }
                __builtin_amdgcn_s_setprio(0);

                asm volatile("" ::: "memory");
            }

            kt += 4;
        } while (kt < nkvA);
    }

    // ---- row-total denominators for both items ----
#pragma unroll
    for (int ri = 0; ri < 2; ++ri) {
        float a = lsA[ri];
        a += __shfl_xor(a, 16); a += __shfl_xor(a, 32);
        lsA[ri] = a;
        float bsum = lsB[ri];
        bsum += __shfl_xor(bsum, 16); bsum += __shfl_xor(bsum, 32);
        lsB[ri] = bsum;
    }
    if (lg == 0) {
#pragma unroll
        for (int ri = 0; ri < 2; ++ri) {
            lldsA[w * 32 + ri * 16 + lr] = lsA[ri];
            lldsB[w * 32 + ri * 16 + lr] = lsB[ri];
        }
    }
    __syncthreads();   // loops done; P regions dead; llds complete

    // ---- merge item A, then item B (reusing scratch) ----
#pragma unroll
    for (int item = 0; item < 2; ++item) {
        const float* lld = item ? lldsB : lldsA;
        const int q0 = item ? q0B : q0A;
        float* o_w = (float*)(smem + w * WREG);  // [32][68] f32
#pragma unroll
        for (int ri = 0; ri < 2; ++ri) {
            const int row = ri * 16 + lr;
#pragma unroll
            for (int dj = 0; dj < 4; ++dj)
                *(f32x4*)&o_w[row * 68 + dj * 16 + lg * 4] = item ? oB[ri][dj] : oA[ri][dj];
        }
        __syncthreads();
        {
            const int row = w * 8 + (l >> 3);
            const int c0 = (l & 7) * 8;
            const float lt = lld[row] + lld[32 + row] + lld[64 + row] + lld[96 + row];
            const float inv = 1.0f / lt;
            ushort4 pk[2];
#pragma unroll
            for (int half = 0; half < 2; ++half) {
                unsigned short u[4];
#pragma unroll
                for (int k = 0; k < 4; ++k) {
                    float acc = 0.f;
#pragma unroll
                    for (int s = 0; s < 4; ++s)
                        acc += ((const float*)(smem + s * WREG))[row * 68 + c0 + half * 4 + k];
                    u[k] = f32_bf16(acc * inv);
                }
                pk[half] = make_ushort4(u[0], u[1], u[2], u[3]);
            }
            unsigned short* dst = zb + (size_t)(b * 2048 + q0 + row) * 768 + h * 64 + c0;
            *(ushort4*)dst = pk[0];
            *(ushort4*)(dst + 4) = pk[1];
        }
        __syncthreads();
    }
}

extern "C" void kernel_launch(void* const* d_in, const int* in_sizes, int n_in,
                              void* d_out, int out_size, void* d_ws, size_t ws_size,
                              hipStream_t stream) {
    (void)in_sizes; (void)n_in; (void)out_size; (void)ws_size;
    const float* x   = (const float*)d_in[0];
    const float* W_Q = (const float*)d_in[1];
    const float* W_K = (const float*)d_in[2];
    const float* W_V = (const float*)d_in[3];
    const float* b_Q = (const float*)d_in[4];
    const float* b_K = (const float*)d_in[5];
    const float* b_V = (const float*)d_in[6];
    const float* W_O = (const float*)d_in[7];
    const float* b_O = (const float*)d_in[8];
    float* out = (float*)d_out;

    char* ws = (char*)d_ws;
    unsigned short* xb    = (unsigned short*)(ws);
    unsigned short* qb    = (unsigned short*)(ws + 6291456);
    unsigned short* khb   = (unsigned short*)(ws + 12582912);
    unsigned short* vtb   = (unsigned short*)(ws + 25165824);
    unsigned short* wqkvT = (unsigned short*)(ws + 31457280);
    unsigned short* woT   = (unsigned short*)(ws + 34996224);
    unsigned short* zb    = xb;  // xb dead after the QKV GEMM

    k_prep<<<3648, 256, 0, stream>>>(x, W_Q, W_K, W_V, W_O, xb, wqkvT, woT);

    k_gemm<128, 64, true><<<dim3(36, 32), 256, 0, stream>>>(xb, wqkvT, b_Q, b_K, b_V,
                                                            qb, khb, vtb, nullptr);

    k_flash<<<dim3(24, 32), 256, 0, stream>>>(qb, khb, vtb, zb);

    k_gemm<64, 64, false><<<dim3(12, 64), 256, 0, stream>>>(zb, woT, b_O, b_O, b_O,
                                                            nullptr, nullptr, nullptr, out);
}